// Round 11
// baseline (503.349 us; speedup 1.0000x reference)
//
#include <hip/hip_runtime.h>
#include <hip/hip_bf16.h>

#define NNODES 50000
#define NEDGES 150000
#define DFEAT  512
#define HID    512
#define NCLS   47
#define ELLW   32

typedef __hip_bfloat16 bf16;
typedef __attribute__((ext_vector_type(8))) short short8;
typedef __attribute__((ext_vector_type(4))) float float4v;

typedef const __attribute__((address_space(1))) unsigned int* gas_t;
typedef __attribute__((address_space(3))) unsigned int* las_t;
__device__ __forceinline__ void load_lds16(const void* g, void* l) {
    __builtin_amdgcn_global_load_lds((gas_t)g, (las_t)l, 16, 0, 0);
}

__device__ __forceinline__ float bfbits_lo(unsigned int w) {
    return __uint_as_float((w & 0xFFFFu) << 16);
}
__device__ __forceinline__ float bfbits_hi(unsigned int w) {
    return __uint_as_float(w & 0xFFFF0000u);
}

__device__ __forceinline__ int eidx(const void* ei, int half, int e, int is64) {
    if (is64) return (int)((const long long*)ei)[(size_t)half * NEDGES + e];
    return ((const int*)ei)[half * NEDGES + e];
}

// ---------------- fused prep kernel: role-dispatched by blockIdx ----------------
// h2-zero role DELETED (fgemm_full plain-stores h2; no atomics, no pre-zero).
#define ZB ((NNODES + 255) / 256)
#define PR_W1T (1 + ZB)
#define PR_B1  (PR_W1T + 1024)
#define PR_W2T (PR_B1 + 2)
#define PR_B2  (PR_W2T + 128)
#define PR_GRID (PR_B2 + 1)

__global__ __launch_bounds__(256) void k_prep0(
    const void* x, const void* ei, const void* W1, const void* b1,
    const void* W2, const void* b2, int* flags, unsigned int* cnt,
    bf16* W1T, float* b1c, bf16* W2T, float* b2c) {
    __shared__ int sh[128];
    __shared__ int shflag;
    const int b = blockIdx.x, t = threadIdx.x;

    if (b >= 1 && b < 1 + ZB) {              // zero cnt
        int i = (b - 1) * 256 + t;
        if (i < NNODES) cnt[i] = 0u;
        return;
    }

    // local bf16 detection (needed by all cvt roles; role 0 also writes flags)
    if (t < 64) {
        const unsigned short* xs = (const unsigned short*)x;
        int c = 0;
        for (int i = t; i < 256; i += 64) {
            unsigned int e = (xs[2 * i] >> 7) & 0xFF;
            c += (e >= 117 && e <= 130) ? 1 : 0;
        }
        sh[t] = c;
        if (b == 0) {
            const int* w = (const int*)ei;
            int o = 0;
            for (int i = 2 * t + 1; i < 512; i += 128) o |= w[i];
            sh[64 + t] = o;
        }
    }
    __syncthreads();
    if (t == 0) {
        int C = 0;
        for (int i = 0; i < 64; i++) C += sh[i];
        shflag = (C > 128) ? 1 : 0;
        if (b == 0) {
            int O = 0;
            for (int i = 0; i < 64; i++) O |= sh[64 + i];
            flags[0] = shflag;
            flags[1] = (O == 0) ? 1 : 0;
        }
    }
    __syncthreads();
    const int isb = shflag;

    if (b == 0) return;

    if (b >= PR_W1T && b < PR_B1) {          // W1 [K][N] -> W1T bf16 [N][K]
        int i = (b - PR_W1T) * 256 + t;
        int k = i / HID, n = i % HID;
        float v = isb ? __bfloat162float(((const bf16*)W1)[i]) : ((const float*)W1)[i];
        W1T[(size_t)n * DFEAT + k] = __float2bfloat16(v);
    } else if (b >= PR_B1 && b < PR_W2T) {   // b1 -> f32
        int i = (b - PR_B1) * 256 + t;
        if (i < HID)
            b1c[i] = isb ? __bfloat162float(((const bf16*)b1)[i]) : ((const float*)b1)[i];
    } else if (b >= PR_W2T && b < PR_B2) {   // W2 [K][47] -> W2T bf16 [64][512] pad
        int i = (b - PR_W2T) * 256 + t;
        int n = i / HID, k = i % HID;
        float v = 0.0f;
        if (n < NCLS) {
            size_t idx = (size_t)k * NCLS + n;
            v = isb ? __bfloat162float(((const bf16*)W2)[idx]) : ((const float*)W2)[idx];
        }
        W2T[(size_t)n * HID + k] = __float2bfloat16(v);
    } else if (b == PR_B2) {                 // b2 -> f32, zero-padded to 64
        if (t < 64)
            b2c[t] = (t < NCLS)
                ? (isb ? __bfloat162float(((const bf16*)b2)[t]) : ((const float*)b2)[t])
                : 0.0f;
    }
}

// ---------------- ELL build: count + fill in ONE kernel ----------------
__global__ void k_fill_ell(const void* ei, int* cnt, int* ell, const int* flags) {
    int e = blockIdx.x * blockDim.x + threadIdx.x;
    if (e >= NEDGES) return;
    int is64 = flags[1];
    int v = eidx(ei, 1, e, is64);
    int u = eidx(ei, 0, e, is64);
    int slot = atomicAdd(&cnt[v], 1);
    if (slot < ELLW) ell[v * ELLW + slot] = u;
}

// ---------------- aggx: ax = D^-1/2 (A+I) D^-1/2 X  (bf16 out) ----------------
// Roofline'd at ~77us (R8: serial/chunk4/chunk8 identical; 200 MB random
// 1KB-row gather service ceiling). Frozen.
__global__ __launch_bounds__(256) void k_aggx(const void* __restrict__ X,
                                              const int* __restrict__ cnt,
                                              const int* __restrict__ ell,
                                              bf16* __restrict__ ax,
                                              const int* __restrict__ flags) {
    int v = blockIdx.x * 4 + (threadIdx.x >> 6);
    int lane = threadIdx.x & 63;
    if (v >= NNODES) return;
    int d8 = lane * 8;
    int degr = cnt[v];
    int deg = degr < ELLW ? degr : ELLW;
    float dv = rsqrtf(1.0f + (float)degr);
    float s2 = dv * dv;
    const int* er = ell + (size_t)v * ELLW;
    float a0, a1, a2, a3, a4, a5, a6, a7;
    if (flags[0]) {
        const bf16* xb = (const bf16*)X;
        uint4 w = *(const uint4*)(xb + (size_t)v * 512 + d8);
        a0 = s2 * bfbits_lo(w.x); a1 = s2 * bfbits_hi(w.x);
        a2 = s2 * bfbits_lo(w.y); a3 = s2 * bfbits_hi(w.y);
        a4 = s2 * bfbits_lo(w.z); a5 = s2 * bfbits_hi(w.z);
        a6 = s2 * bfbits_lo(w.w); a7 = s2 * bfbits_hi(w.w);
        for (int p = 0; p < deg; p += 8) {
            int u[8]; float nw[8];
#pragma unroll
            for (int c = 0; c < 8; ++c) {
                int jp = (p + c < deg) ? p + c : p;
                u[c] = er[jp];
            }
#pragma unroll
            for (int c = 0; c < 8; ++c)
                nw[c] = (p + c < deg) ? rsqrtf(1.0f + (float)cnt[u[c]]) * dv : 0.f;
#pragma unroll
            for (int c = 0; c < 8; ++c) {
                uint4 q = *(const uint4*)(xb + (size_t)u[c] * 512 + d8);
                float nwc = nw[c];
                a0 += nwc * bfbits_lo(q.x); a1 += nwc * bfbits_hi(q.x);
                a2 += nwc * bfbits_lo(q.y); a3 += nwc * bfbits_hi(q.y);
                a4 += nwc * bfbits_lo(q.z); a5 += nwc * bfbits_hi(q.z);
                a6 += nwc * bfbits_lo(q.w); a7 += nwc * bfbits_hi(q.w);
            }
        }
    } else {
        const float* xf = (const float*)X;
        const float* p0 = xf + (size_t)v * 512 + d8;
        float4v f0 = *(const float4v*)p0, f1 = *(const float4v*)(p0 + 4);
        a0 = s2 * f0[0]; a1 = s2 * f0[1]; a2 = s2 * f0[2]; a3 = s2 * f0[3];
        a4 = s2 * f1[0]; a5 = s2 * f1[1]; a6 = s2 * f1[2]; a7 = s2 * f1[3];
        for (int p = 0; p < deg; ++p) {
            int u = er[p];
            float nw = rsqrtf(1.0f + (float)cnt[u]) * dv;
            const float* pu = xf + (size_t)u * 512 + d8;
            float4v g0 = *(const float4v*)pu, g1 = *(const float4v*)(pu + 4);
            a0 += nw * g0[0]; a1 += nw * g0[1]; a2 += nw * g0[2]; a3 += nw * g0[3];
            a4 += nw * g1[0]; a5 += nw * g1[1]; a6 += nw * g1[2]; a7 += nw * g1[3];
        }
    }
    bf16 o[8];
    o[0] = __float2bfloat16(a0); o[1] = __float2bfloat16(a1);
    o[2] = __float2bfloat16(a2); o[3] = __float2bfloat16(a3);
    o[4] = __float2bfloat16(a4); o[5] = __float2bfloat16(a5);
    o[6] = __float2bfloat16(a6); o[7] = __float2bfloat16(a7);
    *(uint4*)(ax + (size_t)v * 512 + d8) = *(uint4*)o;
}

// ---------------- fused GEMM v3: FULL-K 64-row blocks ----------------
// h2 = relu(ax@W1+b1) @ W2 for the block's 64 rows, all 512 mid cols.
// R10 counters: fgemm64 all-pipes-idle with only 16 MFMA/barrier-pair/wave.
// This version: acc[32] tiles/wave -> 64 MFMA/barrier-pair (4x latency-event
// density, same 8 K-steps). A staged via global_load_lds (v3 structure,
// proven); B DIRECT to registers from W1T (v6 evidence: B-direct from L1/L2
// is cheap). Phase 2 chunks R through wave-private LDS (no barriers) and
// accumulates acc2 in REGISTERS across the 4 chunks -> plain h2 stores:
// eliminates h2 atomics, h2 pre-zero, and the 4x ax re-reads.
__global__ __launch_bounds__(256, 2) void k_fgemm_full(
    const bf16* __restrict__ ax, const bf16* __restrict__ W1T,
    const float* __restrict__ b1c, const bf16* __restrict__ W2T,
    float* __restrict__ h2, int rows_per_xcd, int n_row_tiles) {
    const int b = blockIdx.x;
    const int xcd = b & 7;
    const int lr = b >> 3;
    const int row_t = xcd * rows_per_xcd + lr;
    if (row_t >= n_row_tiles) return;

    __shared__ bf16 smem[4096 + 8192];   // As [64][64] 8KB + R 4x[16][128] 16KB
    bf16* As = smem;
    const int tid = threadIdx.x;
    const int wave = tid >> 6, lane = tid & 63;
    const int row0 = row_t * 64;
    const int rb16 = wave * 16;
    const int frow = lane & 15;
    const int fk = lane >> 4;
    bf16* Rw = smem + 4096 + wave * 2048;   // wave-private [16][128]

    float4v acc[32];
#pragma unroll
    for (int j = 0; j < 32; j++) acc[j] = (float4v){0.f, 0.f, 0.f, 0.f};

    // ---- phase 1: acc = ax_tile(64 rows) @ W1T (all 512 cols) ----
    for (int k0 = 0; k0 < DFEAT; k0 += 64) {
        __syncthreads();
#pragma unroll
        for (int t = 0; t < 2; ++t) {             // A: 64 rows, 2 loads/lane
            int g8 = wave * 2 + t;
            int r = g8 * 8 + (lane >> 3);
            int gr = row0 + r; if (gr >= NNODES) gr = NNODES - 1;
            int ck = (lane & 7) ^ (r & 7);
            load_lds16(ax + (size_t)gr * DFEAT + k0 + ck * 8, &As[g8 * 8 * 64]);
        }
        __syncthreads();
#pragma unroll
        for (int ki = 0; ki < 2; ++ki) {
            const int cc = ki * 4 + fk;
            const int r = rb16 + frow;
            short8 a = *(const short8*)&As[r * 64 + (cc ^ (r & 7)) * 8];
#pragma unroll
            for (int jg = 0; jg < 8; ++jg) {
                short8 b4[4];
#pragma unroll
                for (int jj = 0; jj < 4; jj++) {
                    int j = jg * 4 + jj;
                    b4[jj] = *(const short8*)(W1T + (size_t)(j * 16 + frow) * DFEAT
                                              + k0 + ki * 32 + fk * 8);
                }
#pragma unroll
                for (int jj = 0; jj < 4; jj++)
                    acc[jg * 4 + jj] = __builtin_amdgcn_mfma_f32_16x16x32_bf16(
                        a, b4[jj], acc[jg * 4 + jj], 0, 0, 0);
            }
        }
    }

    // ---- phase 2: for each 128-col chunk: bias+relu -> R (wave-private LDS,
    //      no barriers) -> acc2 += R_chunk @ W2T K-slice (register accum) ----
    float4v acc2[4];
#pragma unroll
    for (int j = 0; j < 4; j++) acc2[j] = (float4v){0.f, 0.f, 0.f, 0.f};

#pragma unroll
    for (int jc = 0; jc < 4; ++jc) {
        // R-write: rows fk*4..fk*4+3 (local), cols j*16+frow, XOR-swizzled
#pragma unroll
        for (int j = 0; j < 8; j++) {
            float bias = b1c[jc * 128 + j * 16 + frow];
#pragma unroll
            for (int r = 0; r < 4; r++) {
                int r16 = fk * 4 + r;
                int col = j * 16 + frow;
                float v = acc[jc * 8 + j][r] + bias;
                v = v > 0.f ? v : 0.f;
                int ck2 = (col >> 3) ^ (r16 & 7);
                Rw[r16 * 128 + ck2 * 8 + (col & 7)] = __float2bfloat16(v);
            }
        }
        // R-read + MFMA (same-wave ds ordering via lgkmcnt; cross-lane within
        // wave is instruction-ordered -> safe without barrier)
#pragma unroll
        for (int ks = 0; ks < 4; ++ks) {
            int kk = ks * 32 + fk * 8;
            int p = kk >> 3;
            short8 a2 = *(const short8*)&Rw[frow * 128 + ((p ^ (frow & 7)) * 8)];
            short8 b2f[4];
#pragma unroll
            for (int j = 0; j < 4; j++)
                b2f[j] = *(const short8*)(W2T + (size_t)(j * 16 + frow) * HID
                                          + jc * 128 + kk);
#pragma unroll
            for (int j = 0; j < 4; j++)
                acc2[j] = __builtin_amdgcn_mfma_f32_16x16x32_bf16(a2, b2f[j], acc2[j], 0, 0, 0);
        }
    }

    // ---- epilogue: plain f32 stores (no atomics, full K reduced) ----
#pragma unroll
    for (int r = 0; r < 4; r++) {
        int grow = row0 + rb16 + fk * 4 + r;
        if (grow < NNODES) {
#pragma unroll
            for (int j = 0; j < 4; j++)
                h2[(size_t)grow * 64 + j * 16 + frow] = acc2[j][r];
        }
    }
}

// ---------------- layer2 aggregation: 4 nodes/wave, float4 lanes (frozen) ----
__global__ __launch_bounds__(256) void k_agg2(const float* __restrict__ h2,
                                              const int* __restrict__ cnt,
                                              const int* __restrict__ ell,
                                              const float* __restrict__ b2c,
                                              void* out, const int* flags) {
    int v = blockIdx.x * 16 + (threadIdx.x >> 4);
    int l = threadIdx.x & 15;
    if (v >= NNODES) return;
    int d4 = l * 4;
    int degr = cnt[v];
    int deg = degr < ELLW ? degr : ELLW;
    float dv = rsqrtf(1.0f + (float)degr);
    const int* er = ell + (size_t)v * ELLW;
    float4v w = *(const float4v*)(h2 + (size_t)v * 64 + d4);
    float s2 = dv * dv;
    float a0 = s2 * w[0], a1 = s2 * w[1], a2 = s2 * w[2], a3 = s2 * w[3];
    for (int p = 0; p < deg; p += 4) {
        int u0 = er[p];
        int u1 = er[(p + 1 < deg) ? p + 1 : p];
        int u2 = er[(p + 2 < deg) ? p + 2 : p];
        int u3 = er[(p + 3 < deg) ? p + 3 : p];
        float nw0 = rsqrtf(1.0f + (float)cnt[u0]) * dv;
        float nw1 = (p + 1 < deg) ? rsqrtf(1.0f + (float)cnt[u1]) * dv : 0.f;
        float nw2 = (p + 2 < deg) ? rsqrtf(1.0f + (float)cnt[u2]) * dv : 0.f;
        float nw3 = (p + 3 < deg) ? rsqrtf(1.0f + (float)cnt[u3]) * dv : 0.f;
        float4v q0 = *(const float4v*)(h2 + (size_t)u0 * 64 + d4);
        float4v q1 = *(const float4v*)(h2 + (size_t)u1 * 64 + d4);
        float4v q2 = *(const float4v*)(h2 + (size_t)u2 * 64 + d4);
        float4v q3 = *(const float4v*)(h2 + (size_t)u3 * 64 + d4);
        a0 += nw0 * q0[0] + nw1 * q1[0] + nw2 * q2[0] + nw3 * q3[0];
        a1 += nw0 * q0[1] + nw1 * q1[1] + nw2 * q2[1] + nw3 * q3[1];
        a2 += nw0 * q0[2] + nw1 * q1[2] + nw2 * q2[2] + nw3 * q3[2];
        a3 += nw0 * q0[3] + nw1 * q1[3] + nw2 * q2[3] + nw3 * q3[3];
    }
    a0 += b2c[d4 + 0]; a1 += b2c[d4 + 1]; a2 += b2c[d4 + 2]; a3 += b2c[d4 + 3];
    size_t base = (size_t)v * NCLS;
    if (flags[0]) {
        bf16* ob = (bf16*)out;
        if (d4 + 0 < NCLS) ob[base + d4 + 0] = __float2bfloat16(a0);
        if (d4 + 1 < NCLS) ob[base + d4 + 1] = __float2bfloat16(a1);
        if (d4 + 2 < NCLS) ob[base + d4 + 2] = __float2bfloat16(a2);
        if (d4 + 3 < NCLS) ob[base + d4 + 3] = __float2bfloat16(a3);
    } else {
        float* of = (float*)out;
        if (d4 + 0 < NCLS) of[base + d4 + 0] = a0;
        if (d4 + 1 < NCLS) of[base + d4 + 1] = a1;
        if (d4 + 2 < NCLS) of[base + d4 + 2] = a2;
        if (d4 + 3 < NCLS) of[base + d4 + 3] = a3;
    }
}

extern "C" void kernel_launch(void* const* d_in, const int* in_sizes, int n_in,
                              void* d_out, int out_size, void* d_ws, size_t ws_size,
                              hipStream_t stream) {
    const void* x  = d_in[0];
    const void* ei = d_in[1];
    const void* W1 = d_in[2];
    const void* b1 = d_in[3];
    const void* W2 = d_in[4];
    const void* b2 = d_in[5];

    char* base = (char*)d_ws;
    auto alloc = [&](size_t bytes) -> char* {
        char* p = base;
        base += (bytes + 255) & ~(size_t)255;
        return p;
    };
    int*   flags  = (int*)alloc(64);
    int*   cnt    = (int*)alloc(sizeof(int) * NNODES);
    int*   ell    = (int*)alloc(sizeof(int) * (size_t)NNODES * ELLW);
    bf16*  W1T    = (bf16*)alloc(sizeof(bf16) * DFEAT * HID);
    float* b1c    = (float*)alloc(sizeof(float) * HID);
    bf16*  W2T    = (bf16*)alloc(sizeof(bf16) * 64 * HID);
    float* b2c    = (float*)alloc(sizeof(float) * 64);
    float* h2     = (float*)alloc(sizeof(float) * (size_t)NNODES * 64);
    bf16*  ax     = (bf16*)alloc(sizeof(bf16) * (size_t)NNODES * DFEAT);

    // 1) fused prep: detect + zero(cnt) + weight/bias conversions (no h2 zero)
    k_prep0<<<PR_GRID, 256, 0, stream>>>(x, ei, W1, b1, W2, b2, flags,
                                         (unsigned int*)cnt, W1T, b1c, W2T, b2c);
    // 2) ELL build
    k_fill_ell<<<(NEDGES + 255) / 256, 256, 0, stream>>>(ei, cnt, ell, flags);
    // 3) ax = N·X
    k_aggx<<<(NNODES + 3) / 4, 256, 0, stream>>>(x, cnt, ell, ax, flags);
    // 4) fused full-K: h2 = relu(ax@W1+b1) @ W2  (784 blocks: 8 xcd x 98)
    const int rowblocks = (NNODES + 63) / 64;        // 782
    const int rows_per_xcd = (rowblocks + 7) / 8;    // 98
    k_fgemm_full<<<8 * rows_per_xcd, 256, 0, stream>>>(ax, W1T, b1c, W2T, h2,
                                                       rows_per_xcd, rowblocks);
    // 5) out = N·h2 + b2
    k_agg2<<<(NNODES + 15) / 16, 256, 0, stream>>>(h2, cnt, ell, b2c, d_out, flags);
}

// Round 12
// 297.898 us; speedup vs baseline: 1.6897x; 1.6897x over previous
//
#include <hip/hip_runtime.h>
#include <hip/hip_bf16.h>

#define NNODES 50000
#define NEDGES 150000
#define DFEAT  512
#define HID    512
#define NCLS   47
#define ELLW   32

typedef __hip_bfloat16 bf16;
typedef __attribute__((ext_vector_type(8))) short short8;
typedef __attribute__((ext_vector_type(4))) float float4v;

typedef const __attribute__((address_space(1))) unsigned int* gas_t;
typedef __attribute__((address_space(3))) unsigned int* las_t;
__device__ __forceinline__ void load_lds16(const void* g, void* l) {
    __builtin_amdgcn_global_load_lds((gas_t)g, (las_t)l, 16, 0, 0);
}

__device__ __forceinline__ float bfbits_lo(unsigned int w) {
    return __uint_as_float((w & 0xFFFFu) << 16);
}
__device__ __forceinline__ float bfbits_hi(unsigned int w) {
    return __uint_as_float(w & 0xFFFF0000u);
}

__device__ __forceinline__ int eidx(const void* ei, int half, int e, int is64) {
    if (is64) return (int)((const long long*)ei)[(size_t)half * NEDGES + e];
    return ((const int*)ei)[half * NEDGES + e];
}

// ---------------- fused prep kernel: role-dispatched by blockIdx ----------------
#define ZB ((NNODES + 255) / 256)
#define NZH2 ((NNODES * 64 / 4 + 255) / 256)   // h2 zero: float4 per thread
#define PR_ZH2 (1 + ZB)
#define PR_W1T (PR_ZH2 + NZH2)
#define PR_B1  (PR_W1T + 1024)
#define PR_W2T (PR_B1 + 2)
#define PR_B2  (PR_W2T + 128)
#define PR_GRID (PR_B2 + 1)

__global__ __launch_bounds__(256) void k_prep0(
    const void* x, const void* ei, const void* W1, const void* b1,
    const void* W2, const void* b2, int* flags, unsigned int* cnt,
    bf16* W1T, float* b1c, bf16* W2T, float* b2c, float* h2) {
    __shared__ int sh[128];
    __shared__ int shflag;
    const int b = blockIdx.x, t = threadIdx.x;

    if (b >= 1 && b < 1 + ZB) {              // zero cnt
        int i = (b - 1) * 256 + t;
        if (i < NNODES) cnt[i] = 0u;
        return;
    }
    if (b >= PR_ZH2 && b < PR_W1T) {         // zero h2 (12.8 MB, float4/thread)
        int i = (b - PR_ZH2) * 256 + t;
        if (i < NNODES * 64 / 4)
            ((float4v*)h2)[i] = (float4v){0.f, 0.f, 0.f, 0.f};
        return;
    }

    // local bf16 detection (needed by all cvt roles; role 0 also writes flags)
    if (t < 64) {
        const unsigned short* xs = (const unsigned short*)x;
        int c = 0;
        for (int i = t; i < 256; i += 64) {
            unsigned int e = (xs[2 * i] >> 7) & 0xFF;
            c += (e >= 117 && e <= 130) ? 1 : 0;
        }
        sh[t] = c;
        if (b == 0) {
            const int* w = (const int*)ei;
            int o = 0;
            for (int i = 2 * t + 1; i < 512; i += 128) o |= w[i];
            sh[64 + t] = o;
        }
    }
    __syncthreads();
    if (t == 0) {
        int C = 0;
        for (int i = 0; i < 64; i++) C += sh[i];
        shflag = (C > 128) ? 1 : 0;
        if (b == 0) {
            int O = 0;
            for (int i = 0; i < 64; i++) O |= sh[64 + i];
            flags[0] = shflag;
            flags[1] = (O == 0) ? 1 : 0;
        }
    }
    __syncthreads();
    const int isb = shflag;

    if (b == 0) return;

    if (b >= PR_W1T && b < PR_B1) {          // W1 [K][N] -> W1T bf16 [N][K]
        int i = (b - PR_W1T) * 256 + t;
        int k = i / HID, n = i % HID;
        float v = isb ? __bfloat162float(((const bf16*)W1)[i]) : ((const float*)W1)[i];
        W1T[(size_t)n * DFEAT + k] = __float2bfloat16(v);
    } else if (b >= PR_B1 && b < PR_W2T) {   // b1 -> f32
        int i = (b - PR_B1) * 256 + t;
        if (i < HID)
            b1c[i] = isb ? __bfloat162float(((const bf16*)b1)[i]) : ((const float*)b1)[i];
    } else if (b >= PR_W2T && b < PR_B2) {   // W2 [K][47] -> W2T bf16 [64][512] pad
        int i = (b - PR_W2T) * 256 + t;
        int n = i / HID, k = i % HID;
        float v = 0.0f;
        if (n < NCLS) {
            size_t idx = (size_t)k * NCLS + n;
            v = isb ? __bfloat162float(((const bf16*)W2)[idx]) : ((const float*)W2)[idx];
        }
        W2T[(size_t)n * HID + k] = __float2bfloat16(v);
    } else if (b == PR_B2) {                 // b2 -> f32, zero-padded to 64
        if (t < 64)
            b2c[t] = (t < NCLS)
                ? (isb ? __bfloat162float(((const bf16*)b2)[t]) : ((const float*)b2)[t])
                : 0.0f;
    }
}

// ---------------- ELL build: count + fill in ONE kernel ----------------
__global__ void k_fill_ell(const void* ei, int* cnt, int* ell, const int* flags) {
    int e = blockIdx.x * blockDim.x + threadIdx.x;
    if (e >= NEDGES) return;
    int is64 = flags[1];
    int v = eidx(ei, 1, e, is64);
    int u = eidx(ei, 0, e, is64);
    int slot = atomicAdd(&cnt[v], 1);
    if (slot < ELLW) ell[v * ELLW + slot] = u;
}

// ---------------- aggx: ax = D^-1/2 (A+I) D^-1/2 X  (bf16 out) ----------------
// Roofline'd at ~77us (R8: serial/chunk4/chunk8 identical; 200 MB random
// 1KB-row gather service ceiling). Frozen.
__global__ __launch_bounds__(256) void k_aggx(const void* __restrict__ X,
                                              const int* __restrict__ cnt,
                                              const int* __restrict__ ell,
                                              bf16* __restrict__ ax,
                                              const int* __restrict__ flags) {
    int v = blockIdx.x * 4 + (threadIdx.x >> 6);
    int lane = threadIdx.x & 63;
    if (v >= NNODES) return;
    int d8 = lane * 8;
    int degr = cnt[v];
    int deg = degr < ELLW ? degr : ELLW;
    float dv = rsqrtf(1.0f + (float)degr);
    float s2 = dv * dv;
    const int* er = ell + (size_t)v * ELLW;
    float a0, a1, a2, a3, a4, a5, a6, a7;
    if (flags[0]) {
        const bf16* xb = (const bf16*)X;
        uint4 w = *(const uint4*)(xb + (size_t)v * 512 + d8);
        a0 = s2 * bfbits_lo(w.x); a1 = s2 * bfbits_hi(w.x);
        a2 = s2 * bfbits_lo(w.y); a3 = s2 * bfbits_hi(w.y);
        a4 = s2 * bfbits_lo(w.z); a5 = s2 * bfbits_hi(w.z);
        a6 = s2 * bfbits_lo(w.w); a7 = s2 * bfbits_hi(w.w);
        for (int p = 0; p < deg; p += 8) {
            int u[8]; float nw[8];
#pragma unroll
            for (int c = 0; c < 8; ++c) {
                int jp = (p + c < deg) ? p + c : p;
                u[c] = er[jp];
            }
#pragma unroll
            for (int c = 0; c < 8; ++c)
                nw[c] = (p + c < deg) ? rsqrtf(1.0f + (float)cnt[u[c]]) * dv : 0.f;
#pragma unroll
            for (int c = 0; c < 8; ++c) {
                uint4 q = *(const uint4*)(xb + (size_t)u[c] * 512 + d8);
                float nwc = nw[c];
                a0 += nwc * bfbits_lo(q.x); a1 += nwc * bfbits_hi(q.x);
                a2 += nwc * bfbits_lo(q.y); a3 += nwc * bfbits_hi(q.y);
                a4 += nwc * bfbits_lo(q.z); a5 += nwc * bfbits_hi(q.z);
                a6 += nwc * bfbits_lo(q.w); a7 += nwc * bfbits_hi(q.w);
            }
        }
    } else {
        const float* xf = (const float*)X;
        const float* p0 = xf + (size_t)v * 512 + d8;
        float4v f0 = *(const float4v*)p0, f1 = *(const float4v*)(p0 + 4);
        a0 = s2 * f0[0]; a1 = s2 * f0[1]; a2 = s2 * f0[2]; a3 = s2 * f0[3];
        a4 = s2 * f1[0]; a5 = s2 * f1[1]; a6 = s2 * f1[2]; a7 = s2 * f1[3];
        for (int p = 0; p < deg; ++p) {
            int u = er[p];
            float nw = rsqrtf(1.0f + (float)cnt[u]) * dv;
            const float* pu = xf + (size_t)u * 512 + d8;
            float4v g0 = *(const float4v*)pu, g1 = *(const float4v*)(pu + 4);
            a0 += nw * g0[0]; a1 += nw * g0[1]; a2 += nw * g0[2]; a3 += nw * g0[3];
            a4 += nw * g1[0]; a5 += nw * g1[1]; a6 += nw * g1[2]; a7 += nw * g1[3];
        }
    }
    bf16 o[8];
    o[0] = __float2bfloat16(a0); o[1] = __float2bfloat16(a1);
    o[2] = __float2bfloat16(a2); o[3] = __float2bfloat16(a3);
    o[4] = __float2bfloat16(a4); o[5] = __float2bfloat16(a5);
    o[6] = __float2bfloat16(a6); o[7] = __float2bfloat16(a7);
    *(uint4*)(ax + (size_t)v * 512 + d8) = *(uint4*)o;
}

// ---------------- fused GEMM v2: 64-row tiles (session best) ----------------
__global__ __launch_bounds__(256, 4) void k_fgemm64(
    const bf16* __restrict__ ax, const bf16* __restrict__ W1T,
    const float* __restrict__ b1c, const bf16* __restrict__ W2T,
    float* __restrict__ h2, int rows_per_xcd, int n_row_tiles) {
    const int b = blockIdx.x;
    const int xcd = b & 7;
    const int s = b >> 3;
    const int col_t = s & 3;          // 4 col-chunks of 128 (same-XCD grouping)
    const int lr = s >> 2;
    const int row_t = xcd * rows_per_xcd + lr;
    if (row_t >= n_row_tiles) return;

    __shared__ bf16 smem[12288];      // 24 KiB: As(8K)|Bs(16K) ph1; R(16K) ph2
    bf16* As = smem;                  // [64][64]
    bf16* Bs = smem + 4096;           // [128][64]
    const int tid = threadIdx.x;
    const int wave = tid >> 6, lane = tid & 63;
    const int row0 = row_t * 64;
    const int gc0 = col_t * 128;

    const int rb16 = wave * 16;
    const int frow = lane & 15;
    const int fk = lane >> 4;

    float4v acc[8];
#pragma unroll
    for (int j = 0; j < 8; j++) acc[j] = (float4v){0.f, 0.f, 0.f, 0.f};

    // ---- phase 1: acc = ax_tile(64 rows) @ W1T[gc0..gc0+127] ----
    for (int k0 = 0; k0 < DFEAT; k0 += 64) {
        __syncthreads();
#pragma unroll
        for (int t = 0; t < 2; ++t) {             // A: 64 rows, 2 loads/lane
            int g8 = wave * 2 + t;
            int r = g8 * 8 + (lane >> 3);
            int gr = row0 + r; if (gr >= NNODES) gr = NNODES - 1;
            int ck = (lane & 7) ^ (r & 7);
            load_lds16(ax + (size_t)gr * DFEAT + k0 + ck * 8, &As[g8 * 8 * 64]);
        }
#pragma unroll
        for (int t = 0; t < 4; ++t) {             // B: 128 cols, 4 loads/lane
            int g8 = wave * 4 + t;
            int cl = g8 * 8 + (lane >> 3);
            int ck = (lane & 7) ^ (cl & 7);
            load_lds16(W1T + (size_t)(gc0 + cl) * DFEAT + k0 + ck * 8, &Bs[g8 * 8 * 64]);
        }
        __syncthreads();
#pragma unroll
        for (int ki = 0; ki < 2; ++ki) {
            const int cc = ki * 4 + fk;
            int r = rb16 + frow;
            short8 a = *(const short8*)&As[r * 64 + (cc ^ (r & 7)) * 8];
            short8 b8[8];
#pragma unroll
            for (int j = 0; j < 8; j++) {
                int cl = j * 16 + frow;
                b8[j] = *(const short8*)&Bs[cl * 64 + (cc ^ (cl & 7)) * 8];
            }
#pragma unroll
            for (int j = 0; j < 8; j++)
                acc[j] = __builtin_amdgcn_mfma_f32_16x16x32_bf16(a, b8[j], acc[j], 0, 0, 0);
        }
    }

    // ---- bias + relu -> R [64 rows][128 cols] swizzled into smem ----
    __syncthreads();   // all waves past their last As/Bs reads
    {
        float bias[8];
#pragma unroll
        for (int j = 0; j < 8; j++) bias[j] = b1c[gc0 + j * 16 + frow];
#pragma unroll
        for (int r = 0; r < 4; r++) {
            int row = rb16 + fk * 4 + r;
#pragma unroll
            for (int j = 0; j < 8; j++) {
                int col = j * 16 + frow;
                float v = acc[j][r] + bias[j];
                v = v > 0.f ? v : 0.f;
                int ck2 = (col >> 3) ^ (row & 7);
                smem[row * 128 + ck2 * 8 + (col & 7)] = __float2bfloat16(v);
            }
        }
    }
    __syncthreads();   // (conservative; phase 2 is wave-private)

    // ---- phase 2: acc2 = R(own 16 rows) @ W2T[:, gc0..gc0+127]^T ----
    float4v acc2[4];
#pragma unroll
    for (int j = 0; j < 4; j++) acc2[j] = (float4v){0.f, 0.f, 0.f, 0.f};
#pragma unroll
    for (int ks = 0; ks < 4; ++ks) {
        const int kk = ks * 32 + fk * 8;
        const int p = kk >> 3;
        int row = rb16 + frow;
        short8 a2 = *(const short8*)&smem[row * 128 + ((p ^ (row & 7)) * 8)];
        short8 b2f[4];
#pragma unroll
        for (int j = 0; j < 4; j++) {
            int n = j * 16 + frow;
            b2f[j] = *(const short8*)(W2T + (size_t)n * HID + gc0 + kk);
        }
#pragma unroll
        for (int j = 0; j < 4; j++)
            acc2[j] = __builtin_amdgcn_mfma_f32_16x16x32_bf16(a2, b2f[j], acc2[j], 0, 0, 0);
    }

    // ---- epilogue: atomic accumulate K-slice partial into h2 ----
#pragma unroll
    for (int r = 0; r < 4; r++) {
        int grow = row0 + rb16 + fk * 4 + r;
        if (grow < NNODES) {
#pragma unroll
            for (int j = 0; j < 4; j++)
                atomicAdd(&h2[(size_t)grow * 64 + j * 16 + frow], acc2[j][r]);
        }
    }
}

// ---------------- layer2 aggregation: 4 nodes/wave, float4 lanes ----------
__global__ __launch_bounds__(256) void k_agg2(const float* __restrict__ h2,
                                              const int* __restrict__ cnt,
                                              const int* __restrict__ ell,
                                              const float* __restrict__ b2c,
                                              void* out, const int* flags) {
    int v = blockIdx.x * 16 + (threadIdx.x >> 4);
    int l = threadIdx.x & 15;
    if (v >= NNODES) return;
    int d4 = l * 4;
    int degr = cnt[v];
    int deg = degr < ELLW ? degr : ELLW;
    float dv = rsqrtf(1.0f + (float)degr);
    const int* er = ell + (size_t)v * ELLW;
    float4v w = *(const float4v*)(h2 + (size_t)v * 64 + d4);
    float s2 = dv * dv;
    float a0 = s2 * w[0], a1 = s2 * w[1], a2 = s2 * w[2], a3 = s2 * w[3];
    for (int p = 0; p < deg; p += 4) {
        int u0 = er[p];
        int u1 = er[(p + 1 < deg) ? p + 1 : p];
        int u2 = er[(p + 2 < deg) ? p + 2 : p];
        int u3 = er[(p + 3 < deg) ? p + 3 : p];
        float nw0 = rsqrtf(1.0f + (float)cnt[u0]) * dv;
        float nw1 = (p + 1 < deg) ? rsqrtf(1.0f + (float)cnt[u1]) * dv : 0.f;
        float nw2 = (p + 2 < deg) ? rsqrtf(1.0f + (float)cnt[u2]) * dv : 0.f;
        float nw3 = (p + 3 < deg) ? rsqrtf(1.0f + (float)cnt[u3]) * dv : 0.f;
        float4v q0 = *(const float4v*)(h2 + (size_t)u0 * 64 + d4);
        float4v q1 = *(const float4v*)(h2 + (size_t)u1 * 64 + d4);
        float4v q2 = *(const float4v*)(h2 + (size_t)u2 * 64 + d4);
        float4v q3 = *(const float4v*)(h2 + (size_t)u3 * 64 + d4);
        a0 += nw0 * q0[0] + nw1 * q1[0] + nw2 * q2[0] + nw3 * q3[0];
        a1 += nw0 * q0[1] + nw1 * q1[1] + nw2 * q2[1] + nw3 * q3[1];
        a2 += nw0 * q0[2] + nw1 * q1[2] + nw2 * q2[2] + nw3 * q3[2];
        a3 += nw0 * q0[3] + nw1 * q1[3] + nw2 * q2[3] + nw3 * q3[3];
    }
    a0 += b2c[d4 + 0]; a1 += b2c[d4 + 1]; a2 += b2c[d4 + 2]; a3 += b2c[d4 + 3];
    size_t base = (size_t)v * NCLS;
    if (flags[0]) {
        bf16* ob = (bf16*)out;
        if (d4 + 0 < NCLS) ob[base + d4 + 0] = __float2bfloat16(a0);
        if (d4 + 1 < NCLS) ob[base + d4 + 1] = __float2bfloat16(a1);
        if (d4 + 2 < NCLS) ob[base + d4 + 2] = __float2bfloat16(a2);
        if (d4 + 3 < NCLS) ob[base + d4 + 3] = __float2bfloat16(a3);
    } else {
        float* of = (float*)out;
        if (d4 + 0 < NCLS) of[base + d4 + 0] = a0;
        if (d4 + 1 < NCLS) of[base + d4 + 1] = a1;
        if (d4 + 2 < NCLS) of[base + d4 + 2] = a2;
        if (d4 + 3 < NCLS) of[base + d4 + 3] = a3;
    }
}

extern "C" void kernel_launch(void* const* d_in, const int* in_sizes, int n_in,
                              void* d_out, int out_size, void* d_ws, size_t ws_size,
                              hipStream_t stream) {
    const void* x  = d_in[0];
    const void* ei = d_in[1];
    const void* W1 = d_in[2];
    const void* b1 = d_in[3];
    const void* W2 = d_in[4];
    const void* b2 = d_in[5];

    char* base = (char*)d_ws;
    auto alloc = [&](size_t bytes) -> char* {
        char* p = base;
        base += (bytes + 255) & ~(size_t)255;
        return p;
    };
    int*   flags  = (int*)alloc(64);
    int*   cnt    = (int*)alloc(sizeof(int) * NNODES);
    int*   ell    = (int*)alloc(sizeof(int) * (size_t)NNODES * ELLW);
    bf16*  W1T    = (bf16*)alloc(sizeof(bf16) * DFEAT * HID);
    float* b1c    = (float*)alloc(sizeof(float) * HID);
    bf16*  W2T    = (bf16*)alloc(sizeof(bf16) * 64 * HID);
    float* b2c    = (float*)alloc(sizeof(float) * 64);
    float* h2     = (float*)alloc(sizeof(float) * (size_t)NNODES * 64);
    bf16*  ax     = (bf16*)alloc(sizeof(bf16) * (size_t)NNODES * DFEAT);

    // 1) fused prep: detect + zero(cnt) + zero(h2) + all weight/bias conversions
    k_prep0<<<PR_GRID, 256, 0, stream>>>(x, ei, W1, b1, W2, b2, flags,
                                         (unsigned int*)cnt, W1T, b1c, W2T, b2c, h2);
    // 2) ELL build (count + fill in one kernel; no scans, no dinv)
    k_fill_ell<<<(NEDGES + 255) / 256, 256, 0, stream>>>(ei, cnt, ell, flags);
    // 3) ax = N·X  (reorder: N(XW1) == (NX)W1)
    k_aggx<<<(NNODES + 3) / 4, 256, 0, stream>>>(x, cnt, ell, ax, flags);
    // 4) fused: h2 += relu(ax@W1+b1) @ W2
    const int rowblocks = (NNODES + 63) / 64;        // 782
    const int rows_per_xcd = (rowblocks + 7) / 8;    // 98
    k_fgemm64<<<8 * rows_per_xcd * 4, 256, 0, stream>>>(ax, W1T, b1c, W2T, h2,
                                                        rows_per_xcd, rowblocks);
    // 5) out = N·h2 + b2  (3125 blocks, 16 nodes/block)
    k_agg2<<<(NNODES + 15) / 16, 256, 0, stream>>>(h2, cnt, ell, b2c, d_out, flags);
}